// Round 6
// baseline (520.111 us; speedup 1.0000x reference)
//
#include <hip/hip_runtime.h>
#include <cstdint>

typedef __attribute__((ext_vector_type(8)))  __bf16 bf16x8;
typedef __attribute__((ext_vector_type(16))) float  f32x16;

namespace {

constexpr int NHEADS = 12;
constexpr int TOT    = 138;
constexpr int NLBL   = 30;
constexpr int HID    = 1024;
constexpr int MAXO   = 19;
constexpr int NPAD   = 160;   // padded col count = 5 N-tiles of 32
constexpr int KB     = 16;    // k per MFMA / per pipeline step
constexpr int NT     = HID / KB;       // 64 k-tiles
constexpr int TILE_ELE = NPAD * KB;    // 2560 elements per k-tile per plane
constexpr int EPS    = 161;   // epilogue LDS row stride (odd -> conflict-free)

constexpr int HOFF[NHEADS + 1] = {0, 9, 18, 25, 33, 42, 50, 66, 82, 95, 114, 129, 138};
constexpr int NI[NHEADS] = {9, 9, 7, 8, 9, 8, 16, 16, 13, 19, 15, 9};
constexpr int CAND[TOT] = {
    0, 1, 2, 3, 5, 7, 19, 20, 28,
    0, 1, 2, 3, 5, 7, 19, 20, 28,
    0, 5, 7, 18, 19, 20, 22,
    0, 1, 2, 3, 5, 7, 19, 20,
    0, 1, 2, 3, 5, 7, 19, 20, 28,
    0, 1, 2, 3, 5, 7, 9, 20,
    0, 2, 4, 6, 8, 10, 12, 13, 14, 15, 16, 17, 21, 24, 26, 27,
    0, 4, 6, 8, 10, 11, 12, 13, 14, 15, 17, 23, 24, 26, 27, 29,
    0, 4, 6, 10, 11, 14, 15, 17, 21, 24, 25, 26, 27,
    0, 4, 6, 7, 8, 10, 11, 12, 13, 14, 15, 17, 21, 23, 24, 26, 27, 28, 29,
    0, 4, 6, 8, 10, 11, 12, 13, 14, 15, 16, 17, 21, 27, 29,
    0, 4, 6, 10, 12, 15, 21, 24, 25};

__device__ __forceinline__ float fast_tanh(float x) {
    float e = __expf(2.0f * x);
    return 1.0f - 2.0f * __builtin_amdgcn_rcpf(e + 1.0f);
}

__device__ __forceinline__ void head_of(int c, int& i, int& base) {
    if      (c <   9) { i = 0;  base = 0;   }
    else if (c <  18) { i = 1;  base = 9;   }
    else if (c <  25) { i = 2;  base = 18;  }
    else if (c <  33) { i = 3;  base = 25;  }
    else if (c <  42) { i = 4;  base = 33;  }
    else if (c <  50) { i = 5;  base = 42;  }
    else if (c <  66) { i = 6;  base = 50;  }
    else if (c <  82) { i = 7;  base = 66;  }
    else if (c <  95) { i = 8;  base = 82;  }
    else if (c < 114) { i = 9;  base = 95;  }
    else if (c < 129) { i = 10; base = 114; }
    else              { i = 11; base = 129; }
}

}  // namespace

// ---------------------------------------------------------------------------
// Pack Ws [12][1024][19] -> split-bf16 planes Wh/Wl, layout [64 k-tiles]
// [160 cols][16 k]. Block 0 also zeroes the first 256 B of d_ws (loss
// partials + ticket counter) -- stream order guarantees this precedes fused.
// ---------------------------------------------------------------------------
__global__ void pack_w_split(const float* __restrict__ Ws,
                             __bf16* __restrict__ Wh, __bf16* __restrict__ Wl,
                             unsigned* __restrict__ zero_region) {
    const int t = blockIdx.x;  // k-tile 0..63
    if (t == 0 && threadIdx.x < 64) zero_region[threadIdx.x] = 0u;
    for (int e = threadIdx.x; e < TILE_ELE; e += 256) {
        const int c  = e >> 4;
        const int kk = e & 15;
        float w = 0.0f;
        if (c < TOT) {
            int i, base;
            head_of(c, i, base);
            w = Ws[((size_t)i * HID + t * KB + kk) * MAXO + (c - base)];
        }
        __bf16 hi = (__bf16)w;
        Wh[(size_t)t * TILE_ELE + e] = hi;
        Wl[(size_t)t * TILE_ELE + e] = (__bf16)(w - (float)hi);
    }
}

// ---------------------------------------------------------------------------
// Barrier-free K-loop MFMA kernel. Block = 256 threads = 4 waves, 128 rows;
// each wave owns 32 rows (1 M-tile) fully independently: A-fragments built
// in-register from its own coalesced global loads (lane l: row l&31,
// k-half l>>5 -- the layout round 5 validated), tanh+bf16-split in register.
// NO LDS / NO __syncthreads in the K-loop -> no vmcnt(0) barrier drains
// (round-5 lesson: barrier drain serialized every tile; VALU/MFMA/HBM all
// ~10%). F prefetch distance 2 (4 named bufs), B distance 1 (L2-resident).
// Split-bf16: acc += Ah*Bh + Al*Bh + Ah*Bl (identical numerics to round 5).
// Epilogue: 2 passes through LDS; per-head 19-reg CE slices (acc must stay
// live for waves 2-3 through pass 0, so no a[138] blob); coalesced logit
// stores; ticketed last block computes the final loss (no finalize kernel).
// ---------------------------------------------------------------------------
__global__ __launch_bounds__(256, 2)
void fused_mfma(const float* __restrict__ F,
                const __bf16* __restrict__ Wph,  // [64][160][16] hi plane
                const __bf16* __restrict__ Wpl,  // [64][160][16] lo plane
                const float* __restrict__ bs,    // [12][19]
                const int* __restrict__ head_ids,
                const int* __restrict__ labels,
                float* __restrict__ out,         // [0] loss, [1..] logits
                double* __restrict__ partials,   // 24 doubles in d_ws
                unsigned* __restrict__ ctr)      // ticket counter in d_ws
{
    __shared__ __align__(16) float ep[64 * EPS];   // 41216 B
    __shared__ float zbuf[64 * NLBL];              //  7680 B

    const int tid  = threadIdx.x;
    const int wv   = tid >> 6;
    const int lane = tid & 63;
    const int brow = blockIdx.x * 128;
    const int row0 = brow + wv * 32 + (lane & 31);

    const float* __restrict__ fptr = F + (size_t)row0 * HID + (lane >> 5) * 8;
    const int boff = (lane & 31) * KB + (lane >> 5) * 8;

    f32x16 acc[5];
#pragma unroll
    for (int n = 0; n < 5; ++n)
#pragma unroll
        for (int r = 0; r < 16; ++r) acc[n][r] = 0.0f;

    float4 fb0[2], fb1[2], fb2[2], fb3[2];
    bf16x8 Bh0[5], Bl0[5], Bh1[5], Bl1[5];

#define LOAD_F(D, T)                                                           \
    {                                                                          \
        const float* p_ = fptr + (T) * KB;                                     \
        D[0] = *(const float4*)p_;                                             \
        D[1] = *(const float4*)(p_ + 4);                                       \
    }
#define LOAD_B(BH, BL, T)                                                      \
    {                                                                          \
        const size_t wo_ = (size_t)(T) * TILE_ELE + boff;                      \
        _Pragma("unroll") for (int n = 0; n < 5; ++n) {                        \
            BH[n] = *(const bf16x8*)(Wph + wo_ + n * 512);                     \
            BL[n] = *(const bf16x8*)(Wpl + wo_ + n * 512);                     \
        }                                                                      \
    }

    LOAD_F(fb0, 0);
    LOAD_F(fb1, 1);
    LOAD_B(Bh0, Bl0, 0);

// Step T: issue F load for T+2 and B load for T+1, then tanh+split+pack the
// already-resident tile T and run 15 MFMAs. No barriers -> compiler emits
// counted vmcnt waits; ~2 tiles of loads stay in flight per wave.
#define STEP(FC, FN, BHC, BLC, BHN, BLN, T)                                    \
    {                                                                          \
        if ((T) + 2 < NT) LOAD_F(FN, (T) + 2);                                 \
        if ((T) + 1 < NT) LOAD_B(BHN, BLN, (T) + 1);                           \
        bf16x8 ah, al;                                                         \
        _Pragma("unroll") for (int q = 0; q < 2; ++q) {                        \
            float vx[4] = {FC[q].x, FC[q].y, FC[q].z, FC[q].w};                \
            _Pragma("unroll") for (int e = 0; e < 4; ++e) {                    \
                float hv = fast_tanh(vx[e]);                                   \
                __bf16 hh = (__bf16)hv;                                        \
                ah[q * 4 + e] = hh;                                            \
                al[q * 4 + e] = (__bf16)(hv - (float)hh);                      \
            }                                                                  \
        }                                                                      \
        _Pragma("unroll") for (int n = 0; n < 5; ++n) {                        \
            acc[n] = __builtin_amdgcn_mfma_f32_32x32x16_bf16(                  \
                ah, BHC[n], acc[n], 0, 0, 0);                                  \
            acc[n] = __builtin_amdgcn_mfma_f32_32x32x16_bf16(                  \
                al, BHC[n], acc[n], 0, 0, 0);                                  \
            acc[n] = __builtin_amdgcn_mfma_f32_32x32x16_bf16(                  \
                ah, BLC[n], acc[n], 0, 0, 0);                                  \
        }                                                                      \
    }

#pragma unroll 1
    for (int t = 0; t < NT; t += 4) {
        STEP(fb0, fb2, Bh0, Bl0, Bh1, Bl1, t);
        STEP(fb1, fb3, Bh1, Bl1, Bh0, Bl0, t + 1);
        STEP(fb2, fb0, Bh0, Bl0, Bh1, Bl1, t + 2);
        STEP(fb3, fb1, Bh1, Bl1, Bh0, Bl0, t + 3);
    }
#undef STEP
#undef LOAD_B
#undef LOAD_F

    // ---- epilogue: 2 passes of 64 rows through LDS ----
    // C/D layout (validated r5): col = lane&31, row = (r&3)+8*(r>>2)+4*(lane>>5)
    float wnacc[NHEADS], wdacc[NHEADS];
#pragma unroll
    for (int i = 0; i < NHEADS; ++i) { wnacc[i] = 0.0f; wdacc[i] = 0.0f; }

#pragma unroll 1
    for (int pass = 0; pass < 2; ++pass) {
        __syncthreads();  // ep/zbuf free
        if ((wv >> 1) == pass) {
            const int rb = (wv & 1) * 32;
#pragma unroll
            for (int n = 0; n < 5; ++n)
#pragma unroll
                for (int r = 0; r < 16; ++r) {
                    const int rl = rb + (r & 3) + 8 * (r >> 2) + 4 * (lane >> 5);
                    ep[rl * EPS + n * 32 + (lane & 31)] = acc[n][r];
                }
        }
        __syncthreads();

        if (tid < 64) {
            const int row   = brow + pass * 64 + tid;
            const int label = labels[row];
            const int head  = head_ids[row];

            float v[NLBL];
#pragma unroll
            for (int l = 0; l < NLBL; ++l) v[l] = 1e-7f;

#pragma unroll
            for (int i = 0; i < NHEADS; ++i) {
                float a[MAXO];
#pragma unroll
                for (int j = 0; j < MAXO; ++j)
                    if (j < NI[i]) a[j] = ep[tid * EPS + HOFF[i] + j] + bs[i * MAXO + j];

                int y = 0;
#pragma unroll
                for (int j = 0; j < MAXO; ++j)
                    if (j < NI[i]) { if (CAND[HOFF[i] + j] == label) y = j; }

                float m = a[0];
#pragma unroll
                for (int j = 1; j < MAXO; ++j)
                    if (j < NI[i]) m = fmaxf(m, a[j]);
                float s = 0.0f;
#pragma unroll
                for (int j = 0; j < MAXO; ++j)
                    if (j < NI[i]) s += __expf(a[j] - m);
                float lse = m + __logf(s);

                float ly = a[0];
#pragma unroll
                for (int j = 1; j < MAXO; ++j)
                    if (j < NI[i]) ly = (y == j) ? a[j] : ly;

                float w = (y == 0) ? 0.05f : 1.0f;
                wnacc[i] += w * (lse - ly);
                wdacc[i] += w;

                if (head == i) {
#pragma unroll
                    for (int j = 0; j < MAXO; ++j)
                        if (j < NI[i]) v[CAND[HOFF[i] + j]] = a[j];
                }
            }
#pragma unroll
            for (int l = 0; l < NLBL; ++l) zbuf[tid * NLBL + l] = v[l];
        }
        __syncthreads();

        // coalesced logit store: 64 rows x 30 floats, consecutive dwords
        float* __restrict__ dst = out + 1 + (size_t)(brow + pass * 64) * NLBL;
        for (int q = tid; q < 64 * NLBL; q += 256) dst[q] = zbuf[q];
    }

    // loss: wave 0 holds both passes' contributions
    if (tid < 64) {
#pragma unroll
        for (int i = 0; i < NHEADS; ++i) {
#pragma unroll
            for (int off = 32; off >= 1; off >>= 1) {
                wnacc[i] += __shfl_xor(wnacc[i], off);
                wdacc[i] += __shfl_xor(wdacc[i], off);
            }
        }
        if (tid == 0) {
#pragma unroll
            for (int i = 0; i < NHEADS; ++i) {
                atomicAdd(&partials[2 * i],     (double)wnacc[i]);
                atomicAdd(&partials[2 * i + 1], (double)wdacc[i]);
            }
            __threadfence();
            unsigned ticket = atomicAdd(ctr, 1u);
            if (ticket == gridDim.x - 1) {  // last block: finalize loss
                double tt = 0.0;
                for (int i = 0; i < NHEADS; ++i) {
                    double n = atomicAdd(&partials[2 * i], 0.0);      // coherent read
                    double d = atomicAdd(&partials[2 * i + 1], 0.0);
                    tt += n / d;
                }
                out[0] = (float)tt;
            }
        }
    }
}

// ---------------------------------------------------------------------------
// Fallback (round-3 kernel, validated): only if d_ws can't hold the W planes.
// ---------------------------------------------------------------------------
__global__ __launch_bounds__(128, 1)
void fused_fallback(const float* __restrict__ F,
                    const float* __restrict__ W,
                    const float* __restrict__ bs,
                    const int* __restrict__ head_ids,
                    const int* __restrict__ labels,
                    float* __restrict__ out,
                    double* __restrict__ partials)
{
    constexpr int KC = 8;
    constexpr int KSPLIT = HID / 2;
    const int tid  = threadIdx.x;
    const int wv   = tid >> 6;
    const int lane = tid & 63;
    const int row  = blockIdx.x * 64 + lane;
    const float* __restrict__ frow = F + (size_t)row * HID;

    const int kbeg = wv * KSPLIT, kend = kbeg + KSPLIT;

    float acc[TOT];
#pragma unroll
    for (int c = 0; c < TOT; ++c) acc[c] = 0.0f;

    __align__(16) float cur[KC], nxt[KC];
#pragma unroll
    for (int q = 0; q < KC / 4; ++q)
        *reinterpret_cast<float4*>(&cur[4 * q]) =
            *reinterpret_cast<const float4*>(frow + kbeg + 4 * q);

    for (int k0 = kbeg; k0 < kend; k0 += KC) {
        if (k0 + KC < kend) {
#pragma unroll
            for (int q = 0; q < KC / 4; ++q)
                *reinterpret_cast<float4*>(&nxt[4 * q]) =
                    *reinterpret_cast<const float4*>(frow + k0 + KC + 4 * q);
        }
        float h[KC];
#pragma unroll
        for (int kk = 0; kk < KC; ++kk) h[kk] = fast_tanh(cur[kk]);
#pragma unroll
        for (int kk = 0; kk < KC; ++kk) {
#pragma unroll
            for (int i = 0; i < NHEADS; ++i) {
                const float* __restrict__ wr = W + ((size_t)i * HID + (k0 + kk)) * MAXO;
#pragma unroll
                for (int j = 0; j < MAXO; ++j)
                    if (j < NI[i]) acc[HOFF[i] + j] = fmaf(h[kk], wr[j], acc[HOFF[i] + j]);
            }
        }
        if (k0 + KC < kend) {
#pragma unroll
            for (int kk = 0; kk < KC; ++kk) cur[kk] = nxt[kk];
        }
    }

    constexpr int XST = TOT + 1;
    __shared__ float xch[64 * XST];
    if (wv == 1) {
#pragma unroll
        for (int c = 0; c < TOT; ++c) xch[lane * XST + c] = acc[c];
    }
    __syncthreads();
    if (wv != 0) return;
#pragma unroll
    for (int c = 0; c < TOT; ++c) acc[c] += xch[lane * XST + c];

#pragma unroll
    for (int i = 0; i < NHEADS; ++i)
#pragma unroll
        for (int j = 0; j < MAXO; ++j)
            if (j < NI[i]) acc[HOFF[i] + j] += bs[i * MAXO + j];

    const int label = labels[row];
    const int head  = head_ids[row];
    float wn[NHEADS], wd[NHEADS];
#pragma unroll
    for (int i = 0; i < NHEADS; ++i) {
        int y = 0;
#pragma unroll
        for (int j = 0; j < MAXO; ++j)
            if (j < NI[i]) { if (CAND[HOFF[i] + j] == label) y = j; }
        float m = acc[HOFF[i]];
#pragma unroll
        for (int j = 1; j < MAXO; ++j)
            if (j < NI[i]) m = fmaxf(m, acc[HOFF[i] + j]);
        float s = 0.0f;
#pragma unroll
        for (int j = 0; j < MAXO; ++j)
            if (j < NI[i]) s += __expf(acc[HOFF[i] + j] - m);
        float lse = m + __logf(s);
        float ly = acc[HOFF[i]];
#pragma unroll
        for (int j = 1; j < MAXO; ++j)
            if (j < NI[i]) ly = (y == j) ? acc[HOFF[i] + j] : ly;
        float w = (y == 0) ? 0.05f : 1.0f;
        wn[i] = w * (lse - ly);
        wd[i] = w;
    }
#pragma unroll
    for (int i = 0; i < NHEADS; ++i) {
#pragma unroll
        for (int off = 32; off >= 1; off >>= 1) {
            wn[i] += __shfl_xor(wn[i], off);
            wd[i] += __shfl_xor(wd[i], off);
        }
    }
    if (lane == 0) {
#pragma unroll
        for (int i = 0; i < NHEADS; ++i) {
            atomicAdd(&partials[2 * i],     (double)wn[i]);
            atomicAdd(&partials[2 * i + 1], (double)wd[i]);
        }
    }
    {
        float v[NLBL];
#pragma unroll
        for (int l = 0; l < NLBL; ++l) v[l] = 1e-7f;
#pragma unroll
        for (int i = 0; i < NHEADS; ++i) {
            if (head == i) {
#pragma unroll
                for (int j = 0; j < MAXO; ++j)
                    if (j < NI[i]) v[CAND[HOFF[i] + j]] = acc[HOFF[i] + j];
            }
        }
        float* __restrict__ dst = out + 1 + (size_t)row * NLBL;
#pragma unroll
        for (int l = 0; l < NLBL; ++l) dst[l] = v[l];
    }
}

__global__ void finalize(const double* __restrict__ partials, float* __restrict__ out) {
    double t = 0.0;
    for (int i = 0; i < NHEADS; ++i) t += partials[2 * i] / partials[2 * i + 1];
    out[0] = (float)t;
}

extern "C" void kernel_launch(void* const* d_in, const int* in_sizes, int n_in,
                              void* d_out, int out_size, void* d_ws, size_t ws_size,
                              hipStream_t stream) {
    const float* F        = (const float*)d_in[0];
    const float* Ws       = (const float*)d_in[1];
    const float* bs       = (const float*)d_in[2];
    const int*   head_ids = (const int*)d_in[3];
    const int*   labels   = (const int*)d_in[4];
    float* out = (float*)d_out;

    double*   partials = (double*)d_ws;                 // bytes 0..191
    unsigned* ctr      = (unsigned*)((char*)d_ws + 192); // ticket
    const size_t plane_bytes = (size_t)NT * TILE_ELE * sizeof(__bf16);  // 327680
    __bf16* Wph = (__bf16*)((char*)d_ws + 256);
    __bf16* Wpl = (__bf16*)((char*)d_ws + 256 + plane_bytes);
    const size_t need = 256 + 2 * plane_bytes;

    const int B = in_sizes[3];  // 65536

    if (ws_size >= need) {
        // pack_w_split block 0 zeroes partials+ctr (stream-ordered before fused)
        pack_w_split<<<NT, 256, 0, stream>>>(Ws, Wph, Wpl, (unsigned*)d_ws);
        fused_mfma<<<B / 128, 256, 0, stream>>>(F, Wph, Wpl, bs, head_ids, labels,
                                                out, partials, ctr);
    } else {
        hipMemsetAsync(d_ws, 0, 2 * NHEADS * sizeof(double), stream);
        fused_fallback<<<B / 64, 128, 0, stream>>>(F, Ws, bs, head_ids, labels, out, partials);
        finalize<<<1, 1, 0, stream>>>(partials, out);
    }
}